// Round 1
// baseline (996.812 us; speedup 1.0000x reference)
//
#include <hip/hip_runtime.h>
#include <hip/hip_bf16.h>

#define NCC 4
#define LL 3
#define CCC 32
#define VVV 512
#define HHH 512
#define ROWS_TOTAL 16384   // B*T*N = 32*64*8
#define CONDW 768          // H + 2*NC*C

typedef short bf16x8 __attribute__((ext_vector_type(8)));
typedef float f32x4 __attribute__((ext_vector_type(4)));

// ---- fp32 -> bf16 weight conversion (keeps W [2048][K] row-major layout) ----
__global__ void convert_w(const float* __restrict__ src, __hip_bfloat16* __restrict__ dst, int n) {
    int i = (blockIdx.x * blockDim.x + threadIdx.x) * 4;
    if (i + 3 < n) {
        const float4 v = *reinterpret_cast<const float4*>(src + i);
        dst[i + 0] = __float2bfloat16(v.x);
        dst[i + 1] = __float2bfloat16(v.y);
        dst[i + 2] = __float2bfloat16(v.z);
        dst[i + 3] = __float2bfloat16(v.w);
    }
}

// ---- build cond = [x | hard0 | hard1] (bf16) + comm_output (fp32 exact) ----
// one block per row, 128 threads
__global__ void build_cond(const float* __restrict__ x,
                           const int* __restrict__ comms,
                           const float* __restrict__ codebook,
                           __hip_bfloat16* __restrict__ cond,
                           float* __restrict__ comm_out,
                           float* __restrict__ lp_out,
                           float* __restrict__ ent_out) {
    const int r = blockIdx.x;
    const int t = threadIdx.x;   // 0..127
    // x slice -> cond[0:512] (bf16)
    const float4 v = reinterpret_cast<const float4*>(x + (size_t)r * HHH)[t];
    __hip_bfloat16* crow = cond + (size_t)r * CONDW;
    crow[t * 4 + 0] = __float2bfloat16(v.x);
    crow[t * 4 + 1] = __float2bfloat16(v.y);
    crow[t * 4 + 2] = __float2bfloat16(v.z);
    crow[t * 4 + 3] = __float2bfloat16(v.w);
    // gathers: t indexes (k = t/32, c = t%32) of the NC*C = 128 block
    const int k = t >> 5, c = t & 31;
    float s = 0.f;
    #pragma unroll
    for (int l = 0; l < LL; ++l) {
        const int vi = comms[r * (NCC * LL) + k * LL + l];
        const float val = codebook[((size_t)(l * VVV + vi)) * CCC + c];
        s += val;
        if (l < 2) crow[HHH + l * (NCC * CCC) + t] = __float2bfloat16(val);
    }
    comm_out[(size_t)r * (NCC * CCC) + t] = s;     // forward STE value == hard sum
    if (t == 0) { lp_out[r] = 0.f; ent_out[r] = 0.f; }
}

// ---- fused GEMM(16 rows x 512 cols per block) + log-softmax epilogue ----
// grid: (1024 row-blocks, 4 NC groups, 3 levels), block: 256 (4 waves)
__global__ __launch_bounds__(256) void gemm_softmax(
    const __hip_bfloat16* __restrict__ cond,
    const __hip_bfloat16* __restrict__ wb,
    const float* __restrict__ b0, const float* __restrict__ b1, const float* __restrict__ b2,
    const int* __restrict__ comms,
    float* __restrict__ lp_out, float* __restrict__ ent_out)
{
    const int rb  = blockIdx.x;
    const int g   = blockIdx.y;
    const int lvl = blockIdx.z;
    const int K = HHH + lvl * (NCC * CCC);     // 512 / 640 / 768
    const __hip_bfloat16* W =
        wb + (lvl == 0 ? 0 : (lvl == 1 ? 2048 * 512 : 2048 * 512 + 2048 * 640));
    const float* bias = (lvl == 0) ? b0 : (lvl == 1 ? b1 : b2);

    const int tid  = threadIdx.x;
    const int lane = tid & 63;
    const int w    = tid >> 6;
    const int lrow = lane & 15;       // A row / B col within tile
    const int kgrp = lane >> 4;       // k sub-block
    const int rowBase = rb * 16;
    const int colBase = g * 512 + w * 128;   // wave covers 8 col-tiles of 16

    f32x4 acc[8] = {};
    const __hip_bfloat16* aptr = cond + (size_t)(rowBase + lrow) * CONDW + kgrp * 8;
    const __hip_bfloat16* bptr = W + (size_t)(colBase + lrow) * K + kgrp * 8;

    for (int ks = 0; ks < K; ks += 32) {
        const bf16x8 af = *reinterpret_cast<const bf16x8*>(aptr + ks);
        #pragma unroll
        for (int t = 0; t < 8; ++t) {
            const bf16x8 bfv = *reinterpret_cast<const bf16x8*>(bptr + (size_t)t * 16 * K + ks);
            acc[t] = __builtin_amdgcn_mfma_f32_16x16x32_bf16(af, bfv, acc[t], 0, 0, 0);
        }
    }

    // bias add: logits z = cond@W^T + b. D layout: col = lane&15, row = 4*kgrp + reg
    #pragma unroll
    for (int t = 0; t < 8; ++t) {
        const float bv = bias[colBase + t * 16 + lrow];
        #pragma unroll
        for (int i = 0; i < 4; ++i) acc[t][i] += bv;
    }

    __shared__ float redM[4][16];
    __shared__ float redS[4][16];
    __shared__ float redT[4][16];

    // per-row max over this wave's 128 cols
    float mx[4];
    #pragma unroll
    for (int i = 0; i < 4; ++i) {
        float m = acc[0][i];
        #pragma unroll
        for (int t = 1; t < 8; ++t) m = fmaxf(m, acc[t][i]);
        #pragma unroll
        for (int off = 1; off < 16; off <<= 1) m = fmaxf(m, __shfl_xor(m, off));
        mx[i] = m;
    }
    if (lrow == 0) {
        #pragma unroll
        for (int i = 0; i < 4; ++i) redM[w][kgrp * 4 + i] = mx[i];
    }
    __syncthreads();
    float gm[4];
    #pragma unroll
    for (int i = 0; i < 4; ++i)
        gm[i] = fmaxf(fmaxf(redM[0][kgrp * 4 + i], redM[1][kgrp * 4 + i]),
                      fmaxf(redM[2][kgrp * 4 + i], redM[3][kgrp * 4 + i]));
    __syncthreads();

    // s = sum exp(z - m), t = sum exp(z - m) * z
    float sv[4] = {0.f, 0.f, 0.f, 0.f}, tv[4] = {0.f, 0.f, 0.f, 0.f};
    #pragma unroll
    for (int t = 0; t < 8; ++t) {
        #pragma unroll
        for (int i = 0; i < 4; ++i) {
            const float e = __expf(acc[t][i] - gm[i]);
            sv[i] += e;
            tv[i] += e * acc[t][i];
        }
    }
    #pragma unroll
    for (int i = 0; i < 4; ++i) {
        #pragma unroll
        for (int off = 1; off < 16; off <<= 1) {
            sv[i] += __shfl_xor(sv[i], off);
            tv[i] += __shfl_xor(tv[i], off);
        }
    }
    if (lrow == 0) {
        #pragma unroll
        for (int i = 0; i < 4; ++i) {
            redS[w][kgrp * 4 + i] = sv[i];
            redT[w][kgrp * 4 + i] = tv[i];
        }
    }
    __syncthreads();

    float lz[4];
    #pragma unroll
    for (int i = 0; i < 4; ++i) {
        const int rr = kgrp * 4 + i;
        const float S = redS[0][rr] + redS[1][rr] + redS[2][rr] + redS[3][rr];
        const float T = redT[0][rr] + redT[1][rr] + redT[2][rr] + redT[3][rr];
        lz[i] = gm[i] + __logf(S);
        if (w == 0 && lrow == 0) {
            // entropy contribution: logZ - E[z]
            atomicAdd(ent_out + rowBase + rr, lz[i] - T / S);
        }
    }

    // log-prob of the chosen code for this (row, group, level)
    #pragma unroll
    for (int i = 0; i < 4; ++i) {
        const int rr = kgrp * 4 + i;
        const int target = comms[(rowBase + rr) * (NCC * LL) + g * LL + lvl];
        #pragma unroll
        for (int t = 0; t < 8; ++t) {
            const int col = w * 128 + t * 16 + lrow;   // col within the 512 group
            if (col == target) atomicAdd(lp_out + rowBase + rr, acc[t][i] - lz[i]);
        }
    }
}

extern "C" void kernel_launch(void* const* d_in, const int* in_sizes, int n_in,
                              void* d_out, int out_size, void* d_ws, size_t ws_size,
                              hipStream_t stream) {
    const float* x        = (const float*)d_in[0];
    const int*   comms    = (const int*)d_in[1];
    const float* codebook = (const float*)d_in[2];
    const float* W0 = (const float*)d_in[3];
    const float* b0 = (const float*)d_in[4];
    const float* W1 = (const float*)d_in[5];
    const float* b1 = (const float*)d_in[6];
    const float* W2 = (const float*)d_in[7];
    const float* b2 = (const float*)d_in[8];

    float* out      = (float*)d_out;
    float* comm_out = out;                                    // [16384][128]
    float* lp_out   = out + (size_t)ROWS_TOTAL * 128;         // [16384]
    float* ent_out  = lp_out + ROWS_TOTAL;                    // [16384]

    __hip_bfloat16* wb   = (__hip_bfloat16*)d_ws;             // 3,932,160 bf16
    __hip_bfloat16* cond = (__hip_bfloat16*)((char*)d_ws + 7864320);  // [16384][768] bf16

    const int n0 = 2048 * 512, n1 = 2048 * 640, n2 = 2048 * 768;
    convert_w<<<n0 / 4 / 256, 256, 0, stream>>>(W0, wb, n0);
    convert_w<<<n1 / 4 / 256, 256, 0, stream>>>(W1, wb + n0, n1);
    convert_w<<<n2 / 4 / 256, 256, 0, stream>>>(W2, wb + n0 + n1, n2);

    build_cond<<<ROWS_TOTAL, 128, 0, stream>>>(x, comms, codebook, cond,
                                               comm_out, lp_out, ent_out);

    dim3 grid(ROWS_TOTAL / 16, NCC, LL);
    gemm_softmax<<<grid, 256, 0, stream>>>(cond, wb, b0, b1, b2, comms,
                                           lp_out, ent_out);
}

// Round 3
// 280.997 us; speedup vs baseline: 3.5474x; 3.5474x over previous
//
#include <hip/hip_runtime.h>
#include <hip/hip_bf16.h>

#define NCC 4
#define LL 3
#define CCC 32
#define VVV 512
#define HHH 512
#define ROWS_TOTAL 16384   // B*T*N = 32*64*8
#define CONDW 768          // H + 2*NC*C
#define BKK 32

typedef short bf16x8 __attribute__((ext_vector_type(8)));
typedef float f32x4 __attribute__((ext_vector_type(4)));

__device__ __forceinline__ void gload_lds16(const __hip_bfloat16* g, __hip_bfloat16* l) {
    __builtin_amdgcn_global_load_lds(
        (const __attribute__((address_space(1))) void*)g,
        (__attribute__((address_space(3))) void*)l, 16, 0, 0);
}

// ---- fp32 -> bf16 weight conversion (keeps W [2048][K] row-major layout) ----
__global__ void convert_w(const float* __restrict__ src, __hip_bfloat16* __restrict__ dst, int n) {
    int i = (blockIdx.x * blockDim.x + threadIdx.x) * 4;
    if (i + 3 < n) {
        const float4 v = *reinterpret_cast<const float4*>(src + i);
        dst[i + 0] = __float2bfloat16(v.x);
        dst[i + 1] = __float2bfloat16(v.y);
        dst[i + 2] = __float2bfloat16(v.z);
        dst[i + 3] = __float2bfloat16(v.w);
    }
}

// ---- build cond = [x | hard0 | hard1] (bf16) + comm_output (fp32 exact) ----
__global__ void build_cond(const float* __restrict__ x,
                           const int* __restrict__ comms,
                           const float* __restrict__ codebook,
                           __hip_bfloat16* __restrict__ cond,
                           float* __restrict__ comm_out) {
    const int r = blockIdx.x;
    const int t = threadIdx.x;   // 0..127
    const float4 v = reinterpret_cast<const float4*>(x + (size_t)r * HHH)[t];
    __hip_bfloat16* crow = cond + (size_t)r * CONDW;
    crow[t * 4 + 0] = __float2bfloat16(v.x);
    crow[t * 4 + 1] = __float2bfloat16(v.y);
    crow[t * 4 + 2] = __float2bfloat16(v.z);
    crow[t * 4 + 3] = __float2bfloat16(v.w);
    const int k = t >> 5, c = t & 31;
    float s = 0.f;
    #pragma unroll
    for (int l = 0; l < LL; ++l) {
        const int vi = comms[r * (NCC * LL) + k * LL + l];
        const float val = codebook[((size_t)(l * VVV + vi)) * CCC + c];
        s += val;
        if (l < 2) crow[HHH + l * (NCC * CCC) + t] = __float2bfloat16(val);
    }
    comm_out[(size_t)r * (NCC * CCC) + t] = s;     // forward STE value == hard sum
}

// ---- m97-style tiled GEMM (128x128, BK=32) + per-chunk softmax partials ----
// grid: (128 row-blocks, 16 col-chunks, 3 levels), block: 256 (4 waves, 2x2)
__global__ __launch_bounds__(256) void gemm_partials(
    const __hip_bfloat16* __restrict__ cond,
    const __hip_bfloat16* __restrict__ wb,
    const float* __restrict__ b0, const float* __restrict__ b1, const float* __restrict__ b2,
    const int* __restrict__ comms,
    float4* __restrict__ partials)
{
    const int rb  = blockIdx.x;
    const int y   = blockIdx.y;        // col chunk: g = y>>2, chunk-in-group = y&3
    const int lvl = blockIdx.z;
    const int K = HHH + lvl * (NCC * CCC);
    const __hip_bfloat16* W =
        wb + (lvl == 0 ? 0 : (lvl == 1 ? 2048 * 512 : 2048 * 512 + 2048 * 640));
    const float* bias = (lvl == 0) ? b0 : (lvl == 1 ? b1 : b2);

    const int tid  = threadIdx.x;
    const int lane = tid & 63;
    const int w    = tid >> 6;
    const int wr   = w >> 1, wc = w & 1;
    const int lc   = lane & 15;
    const int kq   = lane >> 4;

    const int rowBase = rb * 128;
    const int colBase = y * 128;

    __shared__ __hip_bfloat16 As[128 * BKK];
    __shared__ __hip_bfloat16 Bs[128 * BKK];
    __shared__ float redM[2][128], redS[2][128], redT[2][128], redTL[128];

    // staging: each wave fills 2x16 rows of As and Bs; lane l -> 16B chunk
    const int srow = lane >> 2;
    const int scol = (lane & 3) * 8;
    const __hip_bfloat16* ga0 = cond + (size_t)(rowBase + w * 32 + srow) * CONDW + scol;
    const __hip_bfloat16* ga1 = cond + (size_t)(rowBase + w * 32 + 16 + srow) * CONDW + scol;
    const __hip_bfloat16* gb0 = W + (size_t)(colBase + w * 32 + srow) * K + scol;
    const __hip_bfloat16* gb1 = W + (size_t)(colBase + w * 32 + 16 + srow) * K + scol;
    __hip_bfloat16* la0 = As + (w * 32) * BKK;
    __hip_bfloat16* la1 = As + (w * 32 + 16) * BKK;
    __hip_bfloat16* lb0 = Bs + (w * 32) * BKK;
    __hip_bfloat16* lb1 = Bs + (w * 32 + 16) * BKK;

    f32x4 acc[4][4] = {};

    for (int ks = 0; ks < K; ks += BKK) {
        if (ks) __syncthreads();
        gload_lds16(ga0 + ks, la0);
        gload_lds16(ga1 + ks, la1);
        gload_lds16(gb0 + ks, lb0);
        gload_lds16(gb1 + ks, lb1);
        __syncthreads();   // compiler emits vmcnt(0) drain before barrier
        bf16x8 a[4], b[4];
        #pragma unroll
        for (int m = 0; m < 4; ++m)
            a[m] = *reinterpret_cast<const bf16x8*>(As + (wr * 64 + m * 16 + lc) * BKK + kq * 8);
        #pragma unroll
        for (int n = 0; n < 4; ++n)
            b[n] = *reinterpret_cast<const bf16x8*>(Bs + (wc * 64 + n * 16 + lc) * BKK + kq * 8);
        #pragma unroll
        for (int m = 0; m < 4; ++m)
            #pragma unroll
            for (int n = 0; n < 4; ++n)
                acc[m][n] = __builtin_amdgcn_mfma_f32_16x16x32_bf16(a[m], b[n], acc[m][n], 0, 0, 0);
    }

    // ---- epilogue: bias + per-row partial softmax over this block's 128 cols ----
    const int g   = y >> 2;
    const int cig = y & 3;
    float bv[4];
    #pragma unroll
    for (int n = 0; n < 4; ++n) bv[n] = bias[colBase + wc * 64 + n * 16 + lc];
    #pragma unroll
    for (int m = 0; m < 4; ++m)
        #pragma unroll
        for (int n = 0; n < 4; ++n)
            #pragma unroll
            for (int i = 0; i < 4; ++i)
                acc[m][n][i] += bv[n];

    #pragma unroll
    for (int m = 0; m < 4; ++m) {
        float mx[4], sv[4] = {0, 0, 0, 0}, tv[4] = {0, 0, 0, 0};
        #pragma unroll
        for (int i = 0; i < 4; ++i) {
            float v = acc[m][0][i];
            #pragma unroll
            for (int n = 1; n < 4; ++n) v = fmaxf(v, acc[m][n][i]);
            #pragma unroll
            for (int off = 1; off < 16; off <<= 1) v = fmaxf(v, __shfl_xor(v, off));
            mx[i] = v;
        }
        #pragma unroll
        for (int i = 0; i < 4; ++i) {
            #pragma unroll
            for (int n = 0; n < 4; ++n) {
                const float e = __expf(acc[m][n][i] - mx[i]);
                sv[i] += e;
                tv[i] += e * acc[m][n][i];
            }
            #pragma unroll
            for (int off = 1; off < 16; off <<= 1) {
                sv[i] += __shfl_xor(sv[i], off);
                tv[i] += __shfl_xor(tv[i], off);
            }
        }
        // target-logit capture (single writer per row across the block)
        #pragma unroll
        for (int i = 0; i < 4; ++i) {
            const int rloc = wr * 64 + m * 16 + kq * 4 + i;
            const int tcol = comms[(size_t)(rowBase + rloc) * (NCC * LL) + g * LL + lvl];
            #pragma unroll
            for (int n = 0; n < 4; ++n) {
                const int colg = cig * 128 + wc * 64 + n * 16 + lc;  // col within 512 group
                if (colg == tcol) redTL[rloc] = acc[m][n][i];
            }
        }
        if (lc == 0) {
            #pragma unroll
            for (int i = 0; i < 4; ++i) {
                const int rloc = wr * 64 + m * 16 + kq * 4 + i;
                redM[wc][rloc] = mx[i];
                redS[wc][rloc] = sv[i];
                redT[wc][rloc] = tv[i];
            }
        }
    }
    __syncthreads();
    if (tid < 128) {
        const int r = tid;
        const float m0 = redM[0][r], m1 = redM[1][r];
        const float M = fmaxf(m0, m1);
        const float e0 = __expf(m0 - M), e1 = __expf(m1 - M);
        const float S = redS[0][r] * e0 + redS[1][r] * e1;
        const float T = redT[0][r] * e0 + redT[1][r] * e1;
        partials[((size_t)lvl * ROWS_TOTAL + rowBase + r) * 16 + y] =
            make_float4(M, S, T, redTL[r]);
    }
}

// ---- exact log-sum-exp merge of the 4 chunks per (row, group, level) ----
__global__ void combine(const float4* __restrict__ partials,
                        const int* __restrict__ comms,
                        float* __restrict__ lp_out, float* __restrict__ ent_out)
{
    const int row = blockIdx.x * 256 + threadIdx.x;
    if (row >= ROWS_TOTAL) return;
    float lp = 0.f, ent = 0.f;
    #pragma unroll
    for (int lvl = 0; lvl < LL; ++lvl) {
        const float4* base = partials + ((size_t)lvl * ROWS_TOTAL + row) * 16;
        #pragma unroll
        for (int g = 0; g < NCC; ++g) {
            const int tcol = comms[(size_t)row * (NCC * LL) + g * LL + lvl];
            float4 c[4];
            #pragma unroll
            for (int k = 0; k < 4; ++k) c[k] = base[g * 4 + k];
            const float M = fmaxf(fmaxf(c[0].x, c[1].x), fmaxf(c[2].x, c[3].x));
            float S = 0.f, T = 0.f, tl = 0.f;
            #pragma unroll
            for (int k = 0; k < 4; ++k) {
                const float e = __expf(c[k].x - M);
                S += c[k].y * e;
                T += c[k].z * e;
                if ((tcol >> 7) == k) tl = c[k].w;
            }
            const float logZ = M + __logf(S);
            ent += logZ - T / S;
            lp += tl - logZ;
        }
    }
    lp_out[row] = lp;
    ent_out[row] = ent;
}

extern "C" void kernel_launch(void* const* d_in, const int* in_sizes, int n_in,
                              void* d_out, int out_size, void* d_ws, size_t ws_size,
                              hipStream_t stream) {
    const float* x        = (const float*)d_in[0];
    const int*   comms    = (const int*)d_in[1];
    const float* codebook = (const float*)d_in[2];
    const float* W0 = (const float*)d_in[3];
    const float* b0 = (const float*)d_in[4];
    const float* W1 = (const float*)d_in[5];
    const float* b1 = (const float*)d_in[6];
    const float* W2 = (const float*)d_in[7];
    const float* b2 = (const float*)d_in[8];

    float* out      = (float*)d_out;
    float* comm_out = out;                                    // [16384][128]
    float* lp_out   = out + (size_t)ROWS_TOTAL * 128;         // [16384]
    float* ent_out  = lp_out + ROWS_TOTAL;                    // [16384]

    __hip_bfloat16* wb   = (__hip_bfloat16*)d_ws;             // 3,932,160 bf16 = 7,864,320 B
    __hip_bfloat16* cond = (__hip_bfloat16*)((char*)d_ws + 7864320);      // [16384][768] bf16
    float4*        parts = (float4*)((char*)d_ws + 7864320 + 25165824);   // [3][16384][16] float4

    const int n0 = 2048 * 512, n1 = 2048 * 640, n2 = 2048 * 768;
    convert_w<<<n0 / 4 / 256, 256, 0, stream>>>(W0, wb, n0);
    convert_w<<<n1 / 4 / 256, 256, 0, stream>>>(W1, wb + n0, n1);
    convert_w<<<n2 / 4 / 256, 256, 0, stream>>>(W2, wb + n0 + n1, n2);

    build_cond<<<ROWS_TOTAL, 128, 0, stream>>>(x, comms, codebook, cond, comm_out);

    dim3 grid(ROWS_TOTAL / 128, 16, LL);
    gemm_partials<<<grid, 256, 0, stream>>>(cond, wb, b0, b1, b2, comms, parts);

    combine<<<ROWS_TOTAL / 256, 256, 0, stream>>>(parts, comms, lp_out, ent_out);
}